// Round 6
// baseline (285.418 us; speedup 1.0000x reference)
//
#include <hip/hip_runtime.h>
#include <hip/hip_bf16.h>
#include <stdint.h>

// Problem constants
#define B_    2
#define S_    2048
#define D_    1024
#define H_    16
#define NTOK  (B_ * S_)   // 4096

typedef __attribute__((ext_vector_type(8))) short bf16x8;
typedef __attribute__((ext_vector_type(4))) float f32x4;
typedef __attribute__((ext_vector_type(2))) float float2v;
typedef __attribute__((ext_vector_type(2))) __bf16 bfv2;

// packed pair fp32 -> 2x bf16 (v_cvt_pk_bf16_f32, RNE)
static __device__ __forceinline__ unsigned int pkbf(float a, float b) {
    float2v fv = {a, b};
    bfv2 r = __builtin_convertvector(fv, bfv2);
    unsigned int u;
    __builtin_memcpy(&u, &r, 4);
    return u;
}

// async global->LDS, 16 B per lane; LDS dest = wave-uniform base + lane*16
using g_cu32 = __attribute__((address_space(1))) const unsigned int;
using l_u32  = __attribute__((address_space(3))) unsigned int;
static __device__ __forceinline__ void gld16(const void* g, void* l) {
    __builtin_amdgcn_global_load_lds((g_cu32*)g, (l_u32*)l, 16, 0, 0);
}

// counted vmcnt wait (T4)
template<int N> static __device__ __forceinline__ void wait_vm() {
    if constexpr (N == 0)      asm volatile("s_waitcnt vmcnt(0)" ::: "memory");
    else if constexpr (N == 2) asm volatile("s_waitcnt vmcnt(2)" ::: "memory");
    else if constexpr (N == 3) asm volatile("s_waitcnt vmcnt(3)" ::: "memory");
    else if constexpr (N == 4) asm volatile("s_waitcnt vmcnt(4)" ::: "memory");
    else if constexpr (N == 6) asm volatile("s_waitcnt vmcnt(6)" ::: "memory");
}
static __device__ __forceinline__ void wait_lgkm0() {
    asm volatile("s_waitcnt lgkmcnt(0)" ::: "memory");
}

#define QN ((size_t)NTOK * D_)   // 4194304
#define WN ((size_t)D_ * D_)     // 1048576 = 1<<20

struct SwapT { static constexpr bool value = true; };
struct NoSwapT { static constexpr bool value = false; };

// ---------------------------------------------------------------------------
// prep: blocks [0,8192) = fp32->bf16 bulk convert (q,k,v + 4 weights);
//       blocks [8192,9216) = mask tile flags (flags[qt][kt] = any-zero in 64x64).
// ---------------------------------------------------------------------------
__global__ __launch_bounds__(256) void prep_kernel(
    const float* __restrict__ q, const float* __restrict__ k, const float* __restrict__ v,
    const float* __restrict__ Wq, const float* __restrict__ Wk,
    const float* __restrict__ Wv, const float* __restrict__ Wo,
    const int* __restrict__ mask,
    unsigned short* __restrict__ qb, unsigned short* __restrict__ kb,
    unsigned short* __restrict__ vb, unsigned short* __restrict__ wqb,
    unsigned short* __restrict__ wkb, unsigned short* __restrict__ wvb,
    unsigned short* __restrict__ wob, int* __restrict__ flags) {
    __shared__ int anyz;
    if (blockIdx.x < 8192) {
        size_t i = ((size_t)blockIdx.x * 256 + threadIdx.x) * 8;
        const float* s; unsigned short* d; size_t off;
        if (i < QN)          { s = q; d = qb; off = i; }
        else if (i < 2 * QN) { s = k; d = kb; off = i - QN; }
        else if (i < 3 * QN) { s = v; d = vb; off = i - 2 * QN; }
        else {
            size_t j = i - 3 * QN;
            int wi = (int)(j >> 20);
            s = (wi == 0) ? Wq : (wi == 1) ? Wk : (wi == 2) ? Wv : Wo;
            d = (wi == 0) ? wqb : (wi == 1) ? wkb : (wi == 2) ? wvb : wob;
            off = j & (WN - 1);
        }
        float4 a = *(const float4*)(s + off);
        float4 b = *(const float4*)(s + off + 4);
        uint4 pk;
        pk.x = pkbf(a.x, a.y); pk.y = pkbf(a.z, a.w);
        pk.z = pkbf(b.x, b.y); pk.w = pkbf(b.z, b.w);
        *(uint4*)(d + off) = pk;
    } else {
        if (threadIdx.x == 0) anyz = 0;
        __syncthreads();
        int bid2 = blockIdx.x - 8192;
        const int qt = bid2 >> 5, kt = bid2 & 31;
        int az = 0;
        for (int i = threadIdx.x; i < 64 * 64; i += 256) {
            int r = i >> 6, c = i & 63;
            az |= (mask[(size_t)(qt * 64 + r) * S_ + kt * 64 + c] == 0) ? 1 : 0;
        }
        if (az) atomicOr(&anyz, 1);
        __syncthreads();
        if (threadIdx.x == 0) flags[qt * 32 + kt] = anyz;
    }
}

// ---------------------------------------------------------------------------
// gemm_n64: C[M,N] = A[M,K] @ W[N,K]^T + bias (then *scale) for the QKV
// projections. 128x64 tile, 2 waves/block (128 thr), wave-tile 64x64 ->
// per-wave work identical to the 4-wave 128x128 version (16 MFMA, 8 ds_read,
// 6 gld16/step). v6 theory: 5 schedule variants all pinned at ~59 us with 3
// blocks/CU (grid 768 = 3/CU cap); m97 runs the IDENTICAL per-step work 2.1x
// faster with 4 independent blocks/CU. Barrier-synced waves stall together,
// so latency coverage scales with independent block pipelines, not waves.
// -> grid 1536 = 6 blocks/CU (6 independent barrier groups, 12 waves/CU).
// LDS: depth-2 x 12 KB = 24 KB (6 x 24 = 144 <= 160). Dual-barrier counted
// step: vmcnt(6)+bar1 (tile resident), ds_read, lgkmcnt(0)+bar2 (all reads
// done), stage into just-read buffer, MFMA. vmcnt never drains mid-loop.
// modes: 1 = bf16 out (Swap: acc holds C^T frags, vectorized stores),
//        2 = bf16 Vt layout (NoSwap).
// ---------------------------------------------------------------------------
struct GemmArgs {
    const unsigned short* A[3];
    const unsigned short* W[3];
    const float* bias[3];
    void* C[3];
    int mode[3];
    float scale[3];
};

__global__ __launch_bounds__(128, 3) void gemm_n64(GemmArgs ga) {
    constexpr int NK = D_ / 32;    // 32 k-steps
    constexpr int AG = 8;          // A groups (128 rows)
    constexpr int NG = 12;         // total groups (A 0..7, B 8..11)
    constexpr int GPW = 6;         // groups per wave
    // 1-D bijective XCD-chunk swizzle: grid 1536, 192/XCD.
    const int bid = blockIdx.x;
    const int l = (bid & 7) * 192 + (bid >> 3);
    const int z = l >> 9;          // /512
    const int r = l & 511;
    const int bx = r & 31;
    const int by = r >> 5;

    const unsigned short* __restrict__ A = ga.A[z];
    const unsigned short* __restrict__ W = ga.W[z];
    const float* __restrict__ bias = ga.bias[z];
    void* C = ga.C[z];
    const int mode = ga.mode[z];
    const float scl = ga.scale[z];

    __shared__ unsigned short Ls[2][NG * 512];

    const int t    = threadIdx.x;
    const int lane = t & 63;
    const int w    = t >> 6;       // wave 0..1
    const int fr   = lane & 15;
    const int kq   = lane >> 4;
    const int m0 = bx * 128, n0 = by * 64;

    const int sc = lane >> 4;      // chunk
    const int sr = lane & 15;      // row in group

    // staging: wave w owns groups [6w, 6w+6); group g<8 -> A row block,
    // else W row block (g-8). per-lane global ptr, uniform LDS group base.
    const unsigned short* gp[GPW];
    int ldo[GPW];
#pragma unroll
    for (int j = 0; j < GPW; ++j) {
        int g = w * GPW + j;
        if (g < AG) gp[j] = A + (size_t)(m0 + g * 16 + sr) * D_ + sc * 8;
        else        gp[j] = W + (size_t)(n0 + (g - AG) * 16 + sr) * D_ + sc * 8;
        ldo[j] = g * 512;
    }

    int aOff[4], bOff[4];
#pragma unroll
    for (int mi = 0; mi < 4; ++mi) aOff[mi] = (w * 4 + mi) * 512 + (kq * 16 + fr) * 8;
#pragma unroll
    for (int ni = 0; ni < 4; ++ni) bOff[ni] = (AG + ni) * 512 + (kq * 16 + fr) * 8;

    f32x4 acc[4][4];
#pragma unroll
    for (int i = 0; i < 4; ++i)
#pragma unroll
        for (int j = 0; j < 4; ++j) acc[i][j] = (f32x4)0.0f;

    auto stage = [&](int buf) {
#pragma unroll
        for (int j = 0; j < GPW; ++j) {
            gld16(gp[j], &Ls[buf][ldo[j]]);
            gp[j] += 32;
        }
    };

    auto kloop = [&](auto swc) {
        constexpr bool SW = decltype(swc)::value;
        stage(0);
        stage(1);
        for (int k0 = 0; k0 < NK; ++k0) {
            const int cur = k0 & 1;
            __builtin_amdgcn_sched_barrier(0);
            if (k0 < NK - 1) wait_vm<GPW>();   // stage(k0) resident, k0+1 in flight
            else             wait_vm<0>();
            __builtin_amdgcn_s_barrier();      // ... for all waves
            __builtin_amdgcn_sched_barrier(0);

            bf16x8 af[4], bfr[4];
#pragma unroll
            for (int mi = 0; mi < 4; ++mi) af[mi] = *(const bf16x8*)&Ls[cur][aOff[mi]];
#pragma unroll
            for (int ni = 0; ni < 4; ++ni) bfr[ni] = *(const bf16x8*)&Ls[cur][bOff[ni]];

            wait_lgkm0();                      // own frag reads done
            __builtin_amdgcn_sched_barrier(0); // rule #18: pin MFMA below
            __builtin_amdgcn_s_barrier();      // all waves' reads of buf done
            if (k0 + 2 < NK) stage(cur);       // safe: nobody reads buf now

#pragma unroll
            for (int mi = 0; mi < 4; ++mi)
#pragma unroll
                for (int ni = 0; ni < 4; ++ni) {
                    if constexpr (SW)
                        acc[mi][ni] = __builtin_amdgcn_mfma_f32_16x16x32_bf16(
                            bfr[ni], af[mi], acc[mi][ni], 0, 0, 0);
                    else
                        acc[mi][ni] = __builtin_amdgcn_mfma_f32_16x16x32_bf16(
                            af[mi], bfr[ni], acc[mi][ni], 0, 0, 0);
                }
        }
    };
    if (mode == 2) kloop(NoSwapT{}); else kloop(SwapT{});

    if (mode == 2) {
        // NoSwap orientation: row=token=(lane>>4)*4+reg, col=feature=lane&15
        // Vt[((b*H+h)*64+d)*S + s], 4 consecutive s per lane
        unsigned short* Co = (unsigned short*)C;
#pragma unroll
        for (int ni = 0; ni < 4; ++ni) {
            int col = n0 + ni * 16 + fr;
            float bv = bias[col];
            int hh = col >> 6, d = col & 63;
#pragma unroll
            for (int mi = 0; mi < 4; ++mi) {
                int tok = m0 + w * 64 + mi * 16 + kq * 4;
                int bb = tok >> 11, sbase = tok & (S_ - 1);
                uint2 pk;
                pk.x = pkbf((acc[mi][ni][0] + bv) * scl, (acc[mi][ni][1] + bv) * scl);
                pk.y = pkbf((acc[mi][ni][2] + bv) * scl, (acc[mi][ni][3] + bv) * scl);
                *(uint2*)(Co + ((size_t)((bb * H_ + hh) * 64 + d)) * S_ + sbase) = pk;
            }
        }
    } else {
        // Swap: row=token=lane&15, 4 consecutive features per lane
        unsigned short* Co = (unsigned short*)C;
#pragma unroll
        for (int ni = 0; ni < 4; ++ni) {
            int nb = n0 + ni * 16 + kq * 4;
            float4 b4 = *(const float4*)&bias[nb];
#pragma unroll
            for (int mi = 0; mi < 4; ++mi) {
                int m = m0 + w * 64 + mi * 16 + fr;
                uint2 pk;
                pk.x = pkbf((acc[mi][ni][0] + b4.x) * scl, (acc[mi][ni][1] + b4.y) * scl);
                pk.y = pkbf((acc[mi][ni][2] + b4.z) * scl, (acc[mi][ni][3] + b4.w) * scl);
                *(uint2*)(Co + (size_t)m * D_ + nb) = pk;
            }
        }
    }
}

// ---------------------------------------------------------------------------
// gemm_async<64>: output projection (fp32 out). 64x128 tile, 4 waves,
// depth-3 counted-vmcnt pipeline (unchanged from R5; not the current
// bottleneck). mode 0 = fp32 out with swapped operands.
// ---------------------------------------------------------------------------
template<int BMT>
__global__ __launch_bounds__(256, 3) void gemm_async(GemmArgs ga) {
    constexpr int AG = BMT / 16;   // A groups
    constexpr int MI = BMT / 32;   // acc rows per wave
    constexpr int NK = D_ / 32;    // 32 k-steps
    constexpr int LOADS = (BMT == 128) ? 4 : 3;
    constexpr int MT = NTOK / BMT;
    constexpr int PERZ = MT * 8;

    const int bid = blockIdx.x;
    const int nb8 = (int)gridDim.x >> 3;
    const int l = (bid & 7) * nb8 + (bid >> 3);
    const int z = l / PERZ;
    const int r = l % PERZ;
    const int bx = r % MT;
    const int by = r / MT;

    const unsigned short* __restrict__ A = ga.A[z];
    const unsigned short* __restrict__ W = ga.W[z];
    const float* __restrict__ bias = ga.bias[z];
    void* C = ga.C[z];
    const float scl = ga.scale[z];

    __shared__ unsigned short As[3][AG * 512];
    __shared__ unsigned short Bs[3][8 * 512];

    const int t    = threadIdx.x;
    const int lane = t & 63;
    const int w    = t >> 6;
    const int fr   = lane & 15;
    const int kq   = lane >> 4;
    const int wrow = w >> 1, wcol = w & 1;
    const int m0 = bx * BMT, n0 = by * 128;

    const int sc = lane >> 4;
    const int sr = lane & 15;

    const unsigned short* ga0 = A + (size_t)(m0 + w * 16 + sr) * D_ + sc * 8;
    const int la0Off = w * 512;
    const unsigned short* gw0 = W + (size_t)(n0 + (2 * w) * 16 + sr) * D_ + sc * 8;
    const unsigned short* gw1 = gw0 + 16 * D_;
    const int lw0Off = (2 * w) * 512;
    const int lw1Off = (2 * w + 1) * 512;

    int aOff[MI], bOff[4];
#pragma unroll
    for (int mi = 0; mi < MI; ++mi) aOff[mi] = (wrow * MI + mi) * 512 + (kq * 16 + fr) * 8;
#pragma unroll
    for (int ni = 0; ni < 4; ++ni) bOff[ni] = (wcol * 4 + ni) * 512 + (kq * 16 + fr) * 8;

    f32x4 acc[MI][4];
#pragma unroll
    for (int i = 0; i < MI; ++i)
#pragma unroll
        for (int j = 0; j < 4; ++j) acc[i][j] = (f32x4)0.0f;

    auto stage = [&](int buf) {
        gld16(ga0, &As[buf][la0Off]);
        gld16(gw0, &Bs[buf][lw0Off]);
        gld16(gw1, &Bs[buf][lw1Off]);
        ga0 += 32; gw0 += 32; gw1 += 32;
    };

    auto mma_step = [&](int cur) {
        const unsigned short* Ab = As[cur];
        const unsigned short* Bb = Bs[cur];
        bf16x8 af[MI], bfr[4];
#pragma unroll
        for (int mi = 0; mi < MI; ++mi) af[mi] = *(const bf16x8*)&Ab[aOff[mi]];
#pragma unroll
        for (int ni = 0; ni < 4; ++ni) bfr[ni] = *(const bf16x8*)&Bb[bOff[ni]];
#pragma unroll
        for (int mi = 0; mi < MI; ++mi)
#pragma unroll
            for (int ni = 0; ni < 4; ++ni)
                acc[mi][ni] = __builtin_amdgcn_mfma_f32_16x16x32_bf16(
                    bfr[ni], af[mi], acc[mi][ni], 0, 0, 0);
    };

    stage(0);
    stage(1);
    int cur = 0;
    for (int k0 = 0; k0 < NK - 1; ++k0) {
        __builtin_amdgcn_sched_barrier(0);
        wait_vm<LOADS>();
        __builtin_amdgcn_s_barrier();
        __builtin_amdgcn_sched_barrier(0);
        if (k0 + 2 < NK) {
            int pf = (cur >= 1) ? cur - 1 : cur + 2;
            stage(pf);
        }
        mma_step(cur);
        cur = (cur < 2) ? cur + 1 : 0;
    }
    __builtin_amdgcn_sched_barrier(0);
    wait_vm<0>();
    __builtin_amdgcn_s_barrier();
    __builtin_amdgcn_sched_barrier(0);
    mma_step(cur);

    // mode 0 epilogue (swapped): row=token=lane&15, 4 consecutive features
    float* Co = (float*)C;
#pragma unroll
    for (int ni = 0; ni < 4; ++ni) {
        int nb = n0 + wcol * 64 + ni * 16 + kq * 4;
        float4 b4 = *(const float4*)&bias[nb];
#pragma unroll
        for (int mi = 0; mi < MI; ++mi) {
            int m = m0 + wrow * (BMT / 2) + mi * 16 + fr;
            float4 o4;
            o4.x = (acc[mi][ni][0] + b4.x) * scl;
            o4.y = (acc[mi][ni][1] + b4.y) * scl;
            o4.z = (acc[mi][ni][2] + b4.z) * scl;
            o4.w = (acc[mi][ni][3] + b4.w) * scl;
            *(float4*)(Co + (size_t)m * D_ + nb) = o4;
        }
    }
}

// ---------------------------------------------------------------------------
// MFMA flash attention v7: 8 waves x 32 q-rows = 256 q-rows/block.
// Each wave owns TWO 16-row fragment columns (qc=0,1): every K/V-frag read
// feeds 2 MFMAs (halved LDS traffic per unit work vs v6). Grid 256 (1/CU).
// Depth-3 K/V pipeline with counted vmcnt + raw s_barrier.
// XCD swizzle: XCD x -> b = x>>2, 4 heads, all 8 qt (2 MB K/V set in L2).
// LDS = 3*8K(K) + 3*8K(V) + 32K(Ps) = 80 KB -> 1 block/CU (grid-limited).
// ---------------------------------------------------------------------------
__global__ __launch_bounds__(512, 2) void flash4(
    const unsigned short* __restrict__ Qb, const unsigned short* __restrict__ Kb,
    const unsigned short* __restrict__ Vtg, const int* __restrict__ mask,
    const int* __restrict__ flags, unsigned short* __restrict__ Xb) {
    __shared__ unsigned short Ks[3][4096];
    __shared__ unsigned short Vs[3][4096];
    __shared__ unsigned short Ps[16384];

    const int t    = threadIdx.x;
    const int lane = t & 63;
    const int w    = t >> 6;     // wave 0..7
    const int fr   = lane & 15;
    const int kq   = lane >> 4;
    const int bid = blockIdx.x;
    const int swb = ((bid & 7) << 5) | (bid >> 3);
    const int qt = swb & 7, hd = (swb >> 3) & 15, b = swb >> 7;
    const int q0 = qt * 256;
    const int swz = fr & 7;

    // Q B-frags for both 16-row columns (one-time row gather)
    bf16x8 qf[2][2];
#pragma unroll
    for (int qc = 0; qc < 2; ++qc) {
        const unsigned short* qrow_p =
            Qb + (size_t)(b * S_ + q0 + w * 32 + qc * 16 + fr) * D_ + hd * 64;
        qf[qc][0] = *(const bf16x8*)(qrow_p + kq * 8);
        qf[qc][1] = *(const bf16x8*)(qrow_p + 32 + kq * 8);
    }

    // per-(wave,qc) mask-tile flags -> bitmask over kt
    unsigned int fmask[2];
#pragma unroll
    for (int qc = 0; qc < 2; ++qc) {
        int qt64 = qt * 4 + ((2 * w + qc) >> 2);
        int fl = (lane < 32) ? flags[qt64 * 32 + lane] : 0;
        fmask[qc] = (unsigned int)__ballot(fl != 0);
    }

    const unsigned short* kptr =
        Kb + (size_t)(b * S_ + (w >> 1) * 16 + fr) * D_ + hd * 64 + (w & 1) * 32 + kq * 8;
    const unsigned short* vptr =
        Vtg + ((size_t)((b * H_ + hd) * 64 + (w >> 1) * 16 + fr)) * S_ + (w & 1) * 32 + kq * 8;

    // prologue: tiles 0,1 into bufs 0,1 (FIFO: K then V per tile)
    gld16(kptr, (char*)&Ks[0][0] + w * 1024);
    gld16(vptr, (char*)&Vs[0][0] + w * 1024);
    gld16(kptr + (size_t)64 * D_, (char*)&Ks[1][0] + w * 1024);
    gld16(vptr + 64,              (char*)&Vs[1][0] + w * 1024);
    const unsigned short* kpf = kptr + (size_t)128 * D_;
    const unsigned short* vpf = vptr + 128;

    unsigned short* pswr[2][4];
    const unsigned short* psrd[2][2];
#pragma unroll
    for (int qc = 0; qc < 2; ++qc) {
        int row = w * 32 + qc * 16 + fr;
#pragma unroll
        for (int mi = 0; mi < 4; ++mi) {
            int chunk = mi * 2 + (kq >> 1);
            pswr[qc][mi] = &Ps[row * 64 + ((chunk ^ swz) << 3) + ((kq & 1) << 2)];
        }
#pragma unroll
        for (int kk = 0; kk < 2; ++kk) {
            int c = kk * 4 + kq;
            psrd[qc][kk] = &Ps[row * 64 + ((c ^ swz) << 3)];
        }
    }

    const f32x4 zf = (f32x4)0.0f;
    f32x4 o[2][4];
#pragma unroll
    for (int qc = 0; qc < 2; ++qc)
#pragma unroll
        for (int i = 0; i < 4; ++i) o[qc][i] = zf;
    float2v l2[2];
    l2[0] = (float2v){0.0f, 0.0f};
    l2[1] = (float2v){0.0f, 0.0f};

    auto attn_step = [&](int cur, int kt) {
        f32x4 st[2][4];
#pragma unroll
        for (int mi = 0; mi < 4; ++mi) {
            bf16x8 a = *(const bf16x8*)&Ks[cur][mi * 1024 + (kq * 16 + fr) * 8];
            st[0][mi] = __builtin_amdgcn_mfma_f32_16x16x32_bf16(a, qf[0][0], zf, 0, 0, 0);
            st[1][mi] = __builtin_amdgcn_mfma_f32_16x16x32_bf16(a, qf[1][0], zf, 0, 0, 0);
        }
#pragma unroll
        for (int mi = 0; mi < 4; ++mi) {
            bf16x8 a = *(const bf16x8*)&Ks[cur][mi * 1024 + ((4 + kq) * 16 + fr) * 8];
            st[0][mi] = __builtin_amdgcn_mfma_f32_16x16x32_bf16(a, qf[0][1], st[0][mi], 0, 0, 0);
            st[1][mi] = __builtin_amdgcn_mfma_f32_16x16x32_bf16(a, qf[1][1], st[1][mi], 0, 0, 0);
        }

#pragma unroll
        for (int qc = 0; qc < 2; ++qc) {
            if ((fmask[qc] >> kt) & 1u) {
#pragma unroll
                for (int mi = 0; mi < 4; ++mi) {
                    int4 mv = *(const int4*)&mask[(size_t)(q0 + w * 32 + qc * 16 + fr) * S_ +
                                                  kt * 64 + mi * 16 + kq * 4];
                    if (mv.x == 0) st[qc][mi][0] = -3e8f;
                    if (mv.y == 0) st[qc][mi][1] = -3e8f;
                    if (mv.z == 0) st[qc][mi][2] = -3e8f;
                    if (mv.w == 0) st[qc][mi][3] = -3e8f;
                }
            }
        }

#pragma unroll
        for (int qc = 0; qc < 2; ++qc)
#pragma unroll
            for (int mi = 0; mi < 4; ++mi) {
                float e0 = __builtin_amdgcn_exp2f(st[qc][mi][0]);
                float e1 = __builtin_amdgcn_exp2f(st[qc][mi][1]);
                float e2 = __builtin_amdgcn_exp2f(st[qc][mi][2]);
                float e3 = __builtin_amdgcn_exp2f(st[qc][mi][3]);
                l2[qc] += (float2v){e0, e1} + (float2v){e2, e3};
                uint2 pk;
                pk.x = pkbf(e0, e1);
                pk.y = pkbf(e2, e3);
                *(uint2*)pswr[qc][mi] = pk;
            }

#pragma unroll
        for (int kk = 0; kk < 2; ++kk) {
            bf16x8 pb0 = *(const bf16x8*)psrd[0][kk];
            bf16x8 pb1 = *(const bf16x8*)psrd[1][kk];
#pragma unroll
            for (int mi = 0; mi < 4; ++mi) {
                bf16x8 a = *(const bf16x8*)&Vs[cur][mi * 1024 + ((kk * 4 + kq) * 16 + fr) * 8];
                o[0][mi] = __builtin_amdgcn_mfma_f32_16x16x32_bf16(a, pb0, o[0][mi], 0, 0, 0);
                o[1][mi] = __builtin_amdgcn_mfma_f32_16x16x32_bf16(a, pb1, o[1][mi], 0, 0, 0);
            }
        }
    };

    int cur = 0;
    for (int kt = 0; kt < 31; ++kt) {
        __builtin_amdgcn_sched_barrier(0);
        wait_vm<2>();
        __builtin_amdgcn_s_barrier();
        __builtin_amdgcn_sched_barrier(0);
        if (kt < 30) {
            int pf = (cur >= 1) ? cur - 1 : cur + 2;
            gld16(kpf, (char*)&Ks[pf][0] + w * 1024);
            gld16(vpf, (char*)&Vs[pf][0] + w * 1024);
            kpf += (size_t)64 * D_;
            vpf += 64;
        }
        attn_step(cur, kt);
        cur = (cur < 2) ? cur + 1 : 0;
    }
    __builtin_amdgcn_sched_barrier(0);
    wait_vm<0>();
    __builtin_amdgcn_s_barrier();
    __builtin_amdgcn_sched_barrier(0);
    attn_step(cur, 31);

#pragma unroll
    for (int qc = 0; qc < 2; ++qc) {
        float l_i = l2[qc].x + l2[qc].y;
        l_i += __shfl_xor(l_i, 16, 64);
        l_i += __shfl_xor(l_i, 32, 64);
        float rl = 1.0f / l_i;
#pragma unroll
        for (int mi = 0; mi < 4; ++mi) {
            uint2 pk;
            pk.x = pkbf(o[qc][mi][0] * rl, o[qc][mi][1] * rl);
            pk.y = pkbf(o[qc][mi][2] * rl, o[qc][mi][3] * rl);
            *(uint2*)(Xb + (size_t)(b * S_ + q0 + w * 32 + qc * 16 + fr) * D_ +
                      hd * 64 + mi * 16 + kq * 4) = pk;
        }
    }
}

// ---------------------------------------------------------------------------
extern "C" void kernel_launch(void* const* d_in, const int* in_sizes, int n_in,
                              void* d_out, int out_size, void* d_ws, size_t ws_size,
                              hipStream_t stream) {
    const float* q    = (const float*)d_in[0];
    const float* k    = (const float*)d_in[1];
    const float* v    = (const float*)d_in[2];
    const int*   mask = (const int*)d_in[3];
    const float* Wq   = (const float*)d_in[4];
    const float* bq   = (const float*)d_in[5];
    const float* Wk   = (const float*)d_in[6];
    const float* bk   = (const float*)d_in[7];
    const float* Wv   = (const float*)d_in[8];
    const float* bv   = (const float*)d_in[9];
    const float* Wo   = (const float*)d_in[10];
    const float* bo   = (const float*)d_in[11];
    float* out = (float*)d_out;

    // workspace (shorts): qb kb vb | Qf Kf Vt | wqb wkb wvb wob | flags  (~59 MB)
    unsigned short* qb  = (unsigned short*)d_ws;
    unsigned short* kb  = qb + QN;
    unsigned short* vb  = kb + QN;
    unsigned short* Qf  = vb + QN;
    unsigned short* Kf  = Qf + QN;
    unsigned short* Vt  = Kf + QN;
    unsigned short* wqb = Vt + QN;
    unsigned short* wkb = wqb + WN;
    unsigned short* wvb = wkb + WN;
    unsigned short* wob = wvb + WN;
    int* flags = (int*)(wob + WN);

    const float SC = 0.18033688011112042f;  // (1/8) * log2(e)

    prep_kernel<<<9216, 256, 0, stream>>>(q, k, v, Wq, Wk, Wv, Wo, mask,
                                          qb, kb, vb, wqb, wkb, wvb, wob, flags);

    GemmArgs g1;
    g1.A[0] = qb;  g1.W[0] = wqb; g1.bias[0] = bq; g1.C[0] = Qf; g1.mode[0] = 1; g1.scale[0] = SC;
    g1.A[1] = kb;  g1.W[1] = wkb; g1.bias[1] = bk; g1.C[1] = Kf; g1.mode[1] = 1; g1.scale[1] = 1.0f;
    g1.A[2] = vb;  g1.W[2] = wvb; g1.bias[2] = bv; g1.C[2] = Vt; g1.mode[2] = 2; g1.scale[2] = 1.0f;
    gemm_n64<<<1536, 128, 0, stream>>>(g1);

    flash4<<<256, 512, 0, stream>>>(Qf, Kf, Vt, mask, flags, Qf);

    GemmArgs g2;
    g2.A[0] = Qf; g2.W[0] = wob; g2.bias[0] = bo; g2.C[0] = out; g2.mode[0] = 0; g2.scale[0] = 1.0f;
    g2.A[1] = g2.A[2] = nullptr; g2.W[1] = g2.W[2] = nullptr;
    g2.bias[1] = g2.bias[2] = nullptr; g2.C[1] = g2.C[2] = nullptr;
    g2.mode[1] = g2.mode[2] = 0; g2.scale[1] = g2.scale[2] = 1.0f;
    gemm_async<64><<<512, 256, 0, stream>>>(g2);
}

// Round 7
// 272.759 us; speedup vs baseline: 1.0464x; 1.0464x over previous
//
#include <hip/hip_runtime.h>
#include <hip/hip_bf16.h>
#include <stdint.h>

// Problem constants
#define B_    2
#define S_    2048
#define D_    1024
#define H_    16
#define NTOK  (B_ * S_)   // 4096

typedef __attribute__((ext_vector_type(8))) short bf16x8;
typedef __attribute__((ext_vector_type(4))) float f32x4;
typedef __attribute__((ext_vector_type(2))) float float2v;
typedef __attribute__((ext_vector_type(2))) __bf16 bfv2;

// packed pair fp32 -> 2x bf16 (v_cvt_pk_bf16_f32, RNE)
static __device__ __forceinline__ unsigned int pkbf(float a, float b) {
    float2v fv = {a, b};
    bfv2 r = __builtin_convertvector(fv, bfv2);
    unsigned int u;
    __builtin_memcpy(&u, &r, 4);
    return u;
}

// async global->LDS, 16 B per lane; LDS dest = wave-uniform base + lane*16
using g_cu32 = __attribute__((address_space(1))) const unsigned int;
using l_u32  = __attribute__((address_space(3))) unsigned int;
static __device__ __forceinline__ void gld16(const void* g, void* l) {
    __builtin_amdgcn_global_load_lds((g_cu32*)g, (l_u32*)l, 16, 0, 0);
}

// counted vmcnt wait (T4)
template<int N> static __device__ __forceinline__ void wait_vm() {
    if constexpr (N == 0)      asm volatile("s_waitcnt vmcnt(0)" ::: "memory");
    else if constexpr (N == 2) asm volatile("s_waitcnt vmcnt(2)" ::: "memory");
    else if constexpr (N == 3) asm volatile("s_waitcnt vmcnt(3)" ::: "memory");
    else if constexpr (N == 4) asm volatile("s_waitcnt vmcnt(4)" ::: "memory");
}

#define QN ((size_t)NTOK * D_)   // 4194304
#define WN ((size_t)D_ * D_)     // 1048576 = 1<<20

// ---------------------------------------------------------------------------
// prep: blocks [0,8192) = fp32->bf16 bulk convert (q,k,v + 4 weights);
//       blocks [8192,9216) = mask tile flags (flags[qt][kt] = any-zero in 64x64).
// ---------------------------------------------------------------------------
__global__ __launch_bounds__(256) void prep_kernel(
    const float* __restrict__ q, const float* __restrict__ k, const float* __restrict__ v,
    const float* __restrict__ Wq, const float* __restrict__ Wk,
    const float* __restrict__ Wv, const float* __restrict__ Wo,
    const int* __restrict__ mask,
    unsigned short* __restrict__ qb, unsigned short* __restrict__ kb,
    unsigned short* __restrict__ vb, unsigned short* __restrict__ wqb,
    unsigned short* __restrict__ wkb, unsigned short* __restrict__ wvb,
    unsigned short* __restrict__ wob, int* __restrict__ flags) {
    __shared__ int anyz;
    if (blockIdx.x < 8192) {
        size_t i = ((size_t)blockIdx.x * 256 + threadIdx.x) * 8;
        const float* s; unsigned short* d; size_t off;
        if (i < QN)          { s = q; d = qb; off = i; }
        else if (i < 2 * QN) { s = k; d = kb; off = i - QN; }
        else if (i < 3 * QN) { s = v; d = vb; off = i - 2 * QN; }
        else {
            size_t j = i - 3 * QN;
            int wi = (int)(j >> 20);
            s = (wi == 0) ? Wq : (wi == 1) ? Wk : (wi == 2) ? Wv : Wo;
            d = (wi == 0) ? wqb : (wi == 1) ? wkb : (wi == 2) ? wvb : wob;
            off = j & (WN - 1);
        }
        float4 a = *(const float4*)(s + off);
        float4 b = *(const float4*)(s + off + 4);
        uint4 pk;
        pk.x = pkbf(a.x, a.y); pk.y = pkbf(a.z, a.w);
        pk.z = pkbf(b.x, b.y); pk.w = pkbf(b.z, b.w);
        *(uint4*)(d + off) = pk;
    } else {
        if (threadIdx.x == 0) anyz = 0;
        __syncthreads();
        int bid2 = blockIdx.x - 8192;
        const int qt = bid2 >> 5, kt = bid2 & 31;
        int az = 0;
        for (int i = threadIdx.x; i < 64 * 64; i += 256) {
            int r = i >> 6, c = i & 63;
            az |= (mask[(size_t)(qt * 64 + r) * S_ + kt * 64 + c] == 0) ? 1 : 0;
        }
        if (az) atomicOr(&anyz, 1);
        __syncthreads();
        if (threadIdx.x == 0) flags[qt * 32 + kt] = anyz;
    }
}

// ---------------------------------------------------------------------------
// R7 diagnosis: staging rate is ~invariant (6.6-7.7 TB/s across every
// schedule/occupancy tried in R2-R6) -> time ~ staged bytes. Minimize bytes.
//
// gemm_bigM: 256x128 tile for the QKV projections. Staged bytes/z =
// A (N/128=8 re-reads x 8MB) + W (M/256=16 x 2MB) = 96 MB -> 288 MB total
// (vs 393 MB at 128x128, 590 MB at 128x64/R6).
// 8 waves (512 thr), wave grid 4x2, wave-tile 64x64 (proven shape: 16 MFMA,
// 8 ds_read, 3 gld16 per wave per k-step). Depth-3 counted-vmcnt ring,
// 24 KB/buf x 3 = 72 KB LDS. Grid 384 = 1.5 blocks/CU.
// Staging: 24 groups (A:16, B:8) of 16 rows x 32 k, chunk-major; wave w
// loads A groups {2w, 2w+1} + B group {16+w} (3 gld16).
// modes: 1 = bf16 out (Swap: acc = C^T frags -> vectorized uint2 stores),
//        2 = bf16 Vt layout (NoSwap).
// ---------------------------------------------------------------------------
struct GemmArgs {
    const unsigned short* A[3];
    const unsigned short* W[3];
    const float* bias[3];
    void* C[3];
    int mode[3];
    float scale[3];
};

__global__ __launch_bounds__(512, 2) void gemm_bigM(GemmArgs ga) {
    constexpr int NK = D_ / 32;    // 32 k-steps
    constexpr int AG = 16;         // A groups (256 rows)
    constexpr int NG = 24;         // total groups

    // bijective XCD-chunk swizzle: grid 384, 48/XCD; bx inner -> blocks with
    // the same (by,z) adjacent on one XCD (W panel 256 KB stays L2-hot).
    const int bid = blockIdx.x;
    const int l = (bid & 7) * 48 + (bid >> 3);
    const int z = l >> 7;          // /128
    const int r = l & 127;
    const int bx = r & 15;
    const int by = r >> 4;

    const unsigned short* __restrict__ A = ga.A[z];
    const unsigned short* __restrict__ W = ga.W[z];
    const float* __restrict__ bias = ga.bias[z];
    void* C = ga.C[z];
    const int mode = ga.mode[z];
    const float scl = ga.scale[z];

    __shared__ unsigned short Ls[3][NG * 512];   // 24 KB per buffer

    const int t    = threadIdx.x;
    const int lane = t & 63;
    const int w    = t >> 6;       // wave 0..7
    const int fr   = lane & 15;
    const int kq   = lane >> 4;
    const int wrow = w >> 1;       // 0..3
    const int wcol = w & 1;        // 0..1
    const int m0 = bx * 256, n0 = by * 128;

    const int sc = lane >> 4;      // k-chunk in group
    const int sr = lane & 15;      // row in group

    // staging pointers (3 gld16/wave/step)
    const unsigned short* gA0 = A + (size_t)(m0 + (2 * w) * 16 + sr) * D_ + sc * 8;
    const unsigned short* gA1 = gA0 + 16 * D_;
    const unsigned short* gB0 = W + (size_t)(n0 + w * 16 + sr) * D_ + sc * 8;
    const int lA0 = (2 * w) * 512, lA1 = (2 * w + 1) * 512, lB0 = (AG + w) * 512;

    int aOff[4], bOff[4];
#pragma unroll
    for (int mi = 0; mi < 4; ++mi) aOff[mi] = (wrow * 4 + mi) * 512 + (kq * 16 + fr) * 8;
#pragma unroll
    for (int ni = 0; ni < 4; ++ni) bOff[ni] = (AG + wcol * 4 + ni) * 512 + (kq * 16 + fr) * 8;

    f32x4 acc[4][4];
#pragma unroll
    for (int i = 0; i < 4; ++i)
#pragma unroll
        for (int j = 0; j < 4; ++j) acc[i][j] = (f32x4)0.0f;

    auto stage = [&](int buf) {
        gld16(gA0, &Ls[buf][lA0]);
        gld16(gA1, &Ls[buf][lA1]);
        gld16(gB0, &Ls[buf][lB0]);
        gA0 += 32; gA1 += 32; gB0 += 32;
    };

    const bool swp = (mode != 2);

    stage(0);
    stage(1);
    int cur = 0;
    for (int k0 = 0; k0 < NK; ++k0) {
        __builtin_amdgcn_sched_barrier(0);
        if (k0 < NK - 1) wait_vm<3>();        // stage(k0) resident (own loads)
        else             wait_vm<0>();
        __builtin_amdgcn_s_barrier();         // ... for all waves
        __builtin_amdgcn_sched_barrier(0);
        if (k0 + 2 < NK) {
            int pf = (cur >= 1) ? cur - 1 : cur + 2;   // (cur+2)%3
            stage(pf);
        }

        bf16x8 af[4], bfr[4];
#pragma unroll
        for (int mi = 0; mi < 4; ++mi) af[mi] = *(const bf16x8*)&Ls[cur][aOff[mi]];
#pragma unroll
        for (int ni = 0; ni < 4; ++ni) bfr[ni] = *(const bf16x8*)&Ls[cur][bOff[ni]];
        if (swp) {
#pragma unroll
            for (int mi = 0; mi < 4; ++mi)
#pragma unroll
                for (int ni = 0; ni < 4; ++ni)
                    acc[mi][ni] = __builtin_amdgcn_mfma_f32_16x16x32_bf16(
                        bfr[ni], af[mi], acc[mi][ni], 0, 0, 0);
        } else {
#pragma unroll
            for (int mi = 0; mi < 4; ++mi)
#pragma unroll
                for (int ni = 0; ni < 4; ++ni)
                    acc[mi][ni] = __builtin_amdgcn_mfma_f32_16x16x32_bf16(
                        af[mi], bfr[ni], acc[mi][ni], 0, 0, 0);
        }
        cur = (cur < 2) ? cur + 1 : 0;
    }

    if (mode == 2) {
        // NoSwap: row=token=(lane>>4)*4+reg, col=feature=lane&15
        // Vt[((b*H+h)*64+d)*S + s], 4 consecutive s per lane
        unsigned short* Co = (unsigned short*)C;
#pragma unroll
        for (int ni = 0; ni < 4; ++ni) {
            int col = n0 + wcol * 64 + ni * 16 + fr;
            float bv = bias[col];
            int hh = col >> 6, d = col & 63;
#pragma unroll
            for (int mi = 0; mi < 4; ++mi) {
                int tok = m0 + wrow * 64 + mi * 16 + kq * 4;
                int bb = tok >> 11, sbase = tok & (S_ - 1);
                uint2 pk;
                pk.x = pkbf((acc[mi][ni][0] + bv) * scl, (acc[mi][ni][1] + bv) * scl);
                pk.y = pkbf((acc[mi][ni][2] + bv) * scl, (acc[mi][ni][3] + bv) * scl);
                *(uint2*)(Co + ((size_t)((bb * H_ + hh) * 64 + d)) * S_ + sbase) = pk;
            }
        }
    } else {
        // Swap: row=token=lane&15, 4 consecutive features per lane
        unsigned short* Co = (unsigned short*)C;
#pragma unroll
        for (int ni = 0; ni < 4; ++ni) {
            int nb = n0 + wcol * 64 + ni * 16 + kq * 4;
            float4 b4 = *(const float4*)&bias[nb];
#pragma unroll
            for (int mi = 0; mi < 4; ++mi) {
                int m = m0 + wrow * 64 + mi * 16 + fr;
                uint2 pk;
                pk.x = pkbf((acc[mi][ni][0] + b4.x) * scl, (acc[mi][ni][1] + b4.y) * scl);
                pk.y = pkbf((acc[mi][ni][2] + b4.z) * scl, (acc[mi][ni][3] + b4.w) * scl);
                *(uint2*)(Co + (size_t)m * D_ + nb) = pk;
            }
        }
    }
}

// ---------------------------------------------------------------------------
// gemm_out: output projection, 128x128 tile, 4 waves (wave-tile 64x64),
// depth-3 counted-vmcnt ring. Staged bytes = A 8x8 + W 32x2 = 128 MB
// (vs 192 MB at 64x128). Grid 256 = 1/CU; XCD owns one by-column (W panel
// 256 KB L2-hot). fp32 out, swapped operands (C^T frags, float4 stores).
// ---------------------------------------------------------------------------
__global__ __launch_bounds__(256, 3) void gemm_out(GemmArgs ga) {
    constexpr int NK = D_ / 32;
    const int bid = blockIdx.x;
    const int l = (bid & 7) * 32 + (bid >> 3);   // grid 256, 32/XCD
    const int bx = l & 31;
    const int by = l >> 5;

    const unsigned short* __restrict__ A = ga.A[0];
    const unsigned short* __restrict__ W = ga.W[0];
    const float* __restrict__ bias = ga.bias[0];
    float* Co = (float*)ga.C[0];

    __shared__ unsigned short As[3][8 * 512];
    __shared__ unsigned short Bs[3][8 * 512];

    const int t    = threadIdx.x;
    const int lane = t & 63;
    const int w    = t >> 6;
    const int fr   = lane & 15;
    const int kq   = lane >> 4;
    const int wrow = w >> 1, wcol = w & 1;
    const int m0 = bx * 128, n0 = by * 128;

    const int sc = lane >> 4;
    const int sr = lane & 15;

    const unsigned short* ga0 = A + (size_t)(m0 + (2 * w) * 16 + sr) * D_ + sc * 8;
    const unsigned short* ga1 = ga0 + 16 * D_;
    const unsigned short* gw0 = W + (size_t)(n0 + (2 * w) * 16 + sr) * D_ + sc * 8;
    const unsigned short* gw1 = gw0 + 16 * D_;
    const int la0 = (2 * w) * 512, la1 = (2 * w + 1) * 512;
    const int lw0 = (2 * w) * 512, lw1 = (2 * w + 1) * 512;

    int aOff[4], bOff[4];
#pragma unroll
    for (int mi = 0; mi < 4; ++mi) aOff[mi] = (wrow * 4 + mi) * 512 + (kq * 16 + fr) * 8;
#pragma unroll
    for (int ni = 0; ni < 4; ++ni) bOff[ni] = (wcol * 4 + ni) * 512 + (kq * 16 + fr) * 8;

    f32x4 acc[4][4];
#pragma unroll
    for (int i = 0; i < 4; ++i)
#pragma unroll
        for (int j = 0; j < 4; ++j) acc[i][j] = (f32x4)0.0f;

    auto stage = [&](int buf) {
        gld16(ga0, &As[buf][la0]);
        gld16(ga1, &As[buf][la1]);
        gld16(gw0, &Bs[buf][lw0]);
        gld16(gw1, &Bs[buf][lw1]);
        ga0 += 32; ga1 += 32; gw0 += 32; gw1 += 32;
    };

    stage(0);
    stage(1);
    int cur = 0;
    for (int k0 = 0; k0 < NK; ++k0) {
        __builtin_amdgcn_sched_barrier(0);
        if (k0 < NK - 1) wait_vm<4>();
        else             wait_vm<0>();
        __builtin_amdgcn_s_barrier();
        __builtin_amdgcn_sched_barrier(0);
        if (k0 + 2 < NK) {
            int pf = (cur >= 1) ? cur - 1 : cur + 2;
            stage(pf);
        }

        bf16x8 af[4], bfr[4];
#pragma unroll
        for (int mi = 0; mi < 4; ++mi) af[mi] = *(const bf16x8*)&As[cur][aOff[mi]];
#pragma unroll
        for (int ni = 0; ni < 4; ++ni) bfr[ni] = *(const bf16x8*)&Bs[cur][bOff[ni]];
#pragma unroll
        for (int mi = 0; mi < 4; ++mi)
#pragma unroll
            for (int ni = 0; ni < 4; ++ni)
                acc[mi][ni] = __builtin_amdgcn_mfma_f32_16x16x32_bf16(
                    bfr[ni], af[mi], acc[mi][ni], 0, 0, 0);
        cur = (cur < 2) ? cur + 1 : 0;
    }

    // fp32 epilogue (swapped): row=token=lane&15, 4 consecutive features
#pragma unroll
    for (int ni = 0; ni < 4; ++ni) {
        int nb = n0 + wcol * 64 + ni * 16 + kq * 4;
        float4 b4 = *(const float4*)&bias[nb];
#pragma unroll
        for (int mi = 0; mi < 4; ++mi) {
            int m = m0 + wrow * 64 + mi * 16 + fr;
            float4 o4;
            o4.x = acc[mi][ni][0] + b4.x;
            o4.y = acc[mi][ni][1] + b4.y;
            o4.z = acc[mi][ni][2] + b4.z;
            o4.w = acc[mi][ni][3] + b4.w;
            *(float4*)(Co + (size_t)m * D_ + nb) = o4;
        }
    }
}

// ---------------------------------------------------------------------------
// MFMA flash attention v7: 8 waves x 32 q-rows = 256 q-rows/block.
// Each wave owns TWO 16-row fragment columns (qc=0,1): every K/V-frag read
// feeds 2 MFMAs. Grid 256 (1/CU). Depth-3 K/V pipeline, counted vmcnt.
// XCD swizzle: XCD x -> b = x>>2, 4 heads, all 8 qt (2 MB K/V set in L2).
// LDS = 3*8K(K) + 3*8K(V) + 32K(Ps) = 80 KB.
// ---------------------------------------------------------------------------
__global__ __launch_bounds__(512, 2) void flash4(
    const unsigned short* __restrict__ Qb, const unsigned short* __restrict__ Kb,
    const unsigned short* __restrict__ Vtg, const int* __restrict__ mask,
    const int* __restrict__ flags, unsigned short* __restrict__ Xb) {
    __shared__ unsigned short Ks[3][4096];
    __shared__ unsigned short Vs[3][4096];
    __shared__ unsigned short Ps[16384];

    const int t    = threadIdx.x;
    const int lane = t & 63;
    const int w    = t >> 6;     // wave 0..7
    const int fr   = lane & 15;
    const int kq   = lane >> 4;
    const int bid = blockIdx.x;
    const int swb = ((bid & 7) << 5) | (bid >> 3);
    const int qt = swb & 7, hd = (swb >> 3) & 15, b = swb >> 7;
    const int q0 = qt * 256;
    const int swz = fr & 7;

    bf16x8 qf[2][2];
#pragma unroll
    for (int qc = 0; qc < 2; ++qc) {
        const unsigned short* qrow_p =
            Qb + (size_t)(b * S_ + q0 + w * 32 + qc * 16 + fr) * D_ + hd * 64;
        qf[qc][0] = *(const bf16x8*)(qrow_p + kq * 8);
        qf[qc][1] = *(const bf16x8*)(qrow_p + 32 + kq * 8);
    }

    unsigned int fmask[2];
#pragma unroll
    for (int qc = 0; qc < 2; ++qc) {
        int qt64 = qt * 4 + ((2 * w + qc) >> 2);
        int fl = (lane < 32) ? flags[qt64 * 32 + lane] : 0;
        fmask[qc] = (unsigned int)__ballot(fl != 0);
    }

    const unsigned short* kptr =
        Kb + (size_t)(b * S_ + (w >> 1) * 16 + fr) * D_ + hd * 64 + (w & 1) * 32 + kq * 8;
    const unsigned short* vptr =
        Vtg + ((size_t)((b * H_ + hd) * 64 + (w >> 1) * 16 + fr)) * S_ + (w & 1) * 32 + kq * 8;

    gld16(kptr, (char*)&Ks[0][0] + w * 1024);
    gld16(vptr, (char*)&Vs[0][0] + w * 1024);
    gld16(kptr + (size_t)64 * D_, (char*)&Ks[1][0] + w * 1024);
    gld16(vptr + 64,              (char*)&Vs[1][0] + w * 1024);
    const unsigned short* kpf = kptr + (size_t)128 * D_;
    const unsigned short* vpf = vptr + 128;

    unsigned short* pswr[2][4];
    const unsigned short* psrd[2][2];
#pragma unroll
    for (int qc = 0; qc < 2; ++qc) {
        int row = w * 32 + qc * 16 + fr;
#pragma unroll
        for (int mi = 0; mi < 4; ++mi) {
            int chunk = mi * 2 + (kq >> 1);
            pswr[qc][mi] = &Ps[row * 64 + ((chunk ^ swz) << 3) + ((kq & 1) << 2)];
        }
#pragma unroll
        for (int kk = 0; kk < 2; ++kk) {
            int c = kk * 4 + kq;
            psrd[qc][kk] = &Ps[row * 64 + ((c ^ swz) << 3)];
        }
    }

    const f32x4 zf = (f32x4)0.0f;
    f32x4 o[2][4];
#pragma unroll
    for (int qc = 0; qc < 2; ++qc)
#pragma unroll
        for (int i = 0; i < 4; ++i) o[qc][i] = zf;
    float2v l2[2];
    l2[0] = (float2v){0.0f, 0.0f};
    l2[1] = (float2v){0.0f, 0.0f};

    auto attn_step = [&](int cur, int kt) {
        f32x4 st[2][4];
#pragma unroll
        for (int mi = 0; mi < 4; ++mi) {
            bf16x8 a = *(const bf16x8*)&Ks[cur][mi * 1024 + (kq * 16 + fr) * 8];
            st[0][mi] = __builtin_amdgcn_mfma_f32_16x16x32_bf16(a, qf[0][0], zf, 0, 0, 0);
            st[1][mi] = __builtin_amdgcn_mfma_f32_16x16x32_bf16(a, qf[1][0], zf, 0, 0, 0);
        }
#pragma unroll
        for (int mi = 0; mi < 4; ++mi) {
            bf16x8 a = *(const bf16x8*)&Ks[cur][mi * 1024 + ((4 + kq) * 16 + fr) * 8];
            st[0][mi] = __builtin_amdgcn_mfma_f32_16x16x32_bf16(a, qf[0][1], st[0][mi], 0, 0, 0);
            st[1][mi] = __builtin_amdgcn_mfma_f32_16x16x32_bf16(a, qf[1][1], st[1][mi], 0, 0, 0);
        }

#pragma unroll
        for (int qc = 0; qc < 2; ++qc) {
            if ((fmask[qc] >> kt) & 1u) {
#pragma unroll
                for (int mi = 0; mi < 4; ++mi) {
                    int4 mv = *(const int4*)&mask[(size_t)(q0 + w * 32 + qc * 16 + fr) * S_ +
                                                  kt * 64 + mi * 16 + kq * 4];
                    if (mv.x == 0) st[qc][mi][0] = -3e8f;
                    if (mv.y == 0) st[qc][mi][1] = -3e8f;
                    if (mv.z == 0) st[qc][mi][2] = -3e8f;
                    if (mv.w == 0) st[qc][mi][3] = -3e8f;
                }
            }
        }

#pragma unroll
        for (int qc = 0; qc < 2; ++qc)
#pragma unroll
            for (int mi = 0; mi < 4; ++mi) {
                float e0 = __builtin_amdgcn_exp2f(st[qc][mi][0]);
                float e1 = __builtin_amdgcn_exp2f(st[qc][mi][1]);
                float e2 = __builtin_amdgcn_exp2f(st[qc][mi][2]);
                float e3 = __builtin_amdgcn_exp2f(st[qc][mi][3]);
                l2[qc] += (float2v){e0, e1} + (float2v){e2, e3};
                uint2 pk;
                pk.x = pkbf(e0, e1);
                pk.y = pkbf(e2, e3);
                *(uint2*)pswr[qc][mi] = pk;
            }

#pragma unroll
        for (int kk = 0; kk < 2; ++kk) {
            bf16x8 pb0 = *(const bf16x8*)psrd[0][kk];
            bf16x8 pb1 = *(const bf16x8*)psrd[1][kk];
#pragma unroll
            for (int mi = 0; mi < 4; ++mi) {
                bf16x8 a = *(const bf16x8*)&Vs[cur][mi * 1024 + ((kk * 4 + kq) * 16 + fr) * 8];
                o[0][mi] = __builtin_amdgcn_mfma_f32_16x16x32_bf16(a, pb0, o[0][mi], 0, 0, 0);
                o[1][mi] = __builtin_amdgcn_mfma_f32_16x16x32_bf16(a, pb1, o[1][mi], 0, 0, 0);
            }
        }
    };

    int cur = 0;
    for (int kt = 0; kt < 31; ++kt) {
        __builtin_amdgcn_sched_barrier(0);
        wait_vm<2>();
        __builtin_amdgcn_s_barrier();
        __builtin_amdgcn_sched_barrier(0);
        if (kt < 30) {
            int pf = (cur >= 1) ? cur - 1 : cur + 2;
            gld16(kpf, (char*)&Ks[pf][0] + w * 1024);
            gld16(vpf, (char*)&Vs[pf][0] + w * 1024);
            kpf += (size_t)64 * D_;
            vpf += 64;
        }
        attn_step(cur, kt);
        cur = (cur < 2) ? cur + 1 : 0;
    }
    __builtin_amdgcn_sched_barrier(0);
    wait_vm<0>();
    __builtin_amdgcn_s_barrier();
    __builtin_amdgcn_sched_barrier(0);
    attn_step(cur, 31);

#pragma unroll
    for (int qc = 0; qc < 2; ++qc) {
        float l_i = l2[qc].x + l2[qc].y;
        l_i += __shfl_xor(l_i, 16, 64);
        l_i += __shfl_xor(l_i, 32, 64);
        float rl = 1.0f / l_i;
#pragma unroll
        for (int mi = 0; mi < 4; ++mi) {
            uint2 pk;
            pk.x = pkbf(o[qc][mi][0] * rl, o[qc][mi][1] * rl);
            pk.y = pkbf(o[qc][mi][2] * rl, o[qc][mi][3] * rl);
            *(uint2*)(Xb + (size_t)(b * S_ + q0 + w * 32 + qc * 16 + fr) * D_ +
                      hd * 64 + mi * 16 + kq * 4) = pk;
        }
    }
}

// ---------------------------------------------------------------------------
extern "C" void kernel_launch(void* const* d_in, const int* in_sizes, int n_in,
                              void* d_out, int out_size, void* d_ws, size_t ws_size,
                              hipStream_t stream) {
    const float* q    = (const float*)d_in[0];
    const float* k    = (const float*)d_in[1];
    const float* v    = (const float*)d_in[2];
    const int*   mask = (const int*)d_in[3];
    const float* Wq   = (const float*)d_in[4];
    const float* bq   = (const float*)d_in[5];
    const float* Wk   = (const float*)d_in[6];
    const float* bk   = (const float*)d_in[7];
    const float* Wv   = (const float*)d_in[8];
    const float* bv   = (const float*)d_in[9];
    const float* Wo   = (const float*)d_in[10];
    const float* bo   = (const float*)d_in[11];
    float* out = (float*)d_out;

    // workspace (shorts): qb kb vb | Qf Kf Vt | wqb wkb wvb wob | flags  (~59 MB)
    unsigned short* qb  = (unsigned short*)d_ws;
    unsigned short* kb  = qb + QN;
    unsigned short* vb  = kb + QN;
    unsigned short* Qf  = vb + QN;
    unsigned short* Kf  = Qf + QN;
    unsigned short* Vt  = Kf + QN;
    unsigned short* wqb = Vt + QN;
    unsigned short* wkb = wqb + WN;
    unsigned short* wvb = wkb + WN;
    unsigned short* wob = wvb + WN;
    int* flags = (int*)(wob + WN);

    const float SC = 0.18033688011112042f;  // (1/8) * log2(e)

    prep_kernel<<<9216, 256, 0, stream>>>(q, k, v, Wq, Wk, Wv, Wo, mask,
                                          qb, kb, vb, wqb, wkb, wvb, wob, flags);

    GemmArgs g1;
    g1.A[0] = qb;  g1.W[0] = wqb; g1.bias[0] = bq; g1.C[0] = Qf; g1.mode[0] = 1; g1.scale[0] = SC;
    g1.A[1] = kb;  g1.W[1] = wkb; g1.bias[1] = bk; g1.C[1] = Kf; g1.mode[1] = 1; g1.scale[1] = 1.0f;
    g1.A[2] = vb;  g1.W[2] = wvb; g1.bias[2] = bv; g1.C[2] = Vt; g1.mode[2] = 2; g1.scale[2] = 1.0f;
    gemm_bigM<<<384, 512, 0, stream>>>(g1);

    flash4<<<256, 512, 0, stream>>>(Qf, Kf, Vt, mask, flags, Qf);

    GemmArgs g2;
    g2.A[0] = Qf; g2.W[0] = wob; g2.bias[0] = bo; g2.C[0] = out; g2.mode[0] = 0; g2.scale[0] = 1.0f;
    g2.A[1] = g2.A[2] = nullptr; g2.W[1] = g2.W[2] = nullptr;
    g2.bias[1] = g2.bias[2] = nullptr; g2.C[1] = g2.C[2] = nullptr;
    g2.mode[1] = g2.mode[2] = 0; g2.scale[1] = g2.scale[2] = 1.0f;
    gemm_out<<<256, 256, 0, stream>>>(g2);
}